// Round 1
// baseline (200.236 us; speedup 1.0000x reference)
//
#include <hip/hip_runtime.h>
#include <math.h>

// Problem constants (from reference): L=4096, B=4, D=1024, N=16
#define L_SEQ 4096
#define B_SZ 4
#define D_SZ 1024
#define N_MODES 16
#define CH (B_SZ * D_SZ)   // 4096 channels (b,d)
#define ROW (B_SZ * D_SZ)  // stride between consecutive l in x: 4096 floats

// ---------------------------------------------------------------------------
// Precompute per-(d,n) parameters:
//   p  = sigmoid(delta);  q = 1 - p*sigmoid(alpha)
//   w  = p * beta * gamma * scale        (scale = 1/sqrt(N) = 0.25)
//   qLc = q^Lc  (Lc = chunk length, power of 2 -> log2Lc squarings)
// Stored transposed [n][d] so phase kernels load coalesced per-n.
// ---------------------------------------------------------------------------
__global__ void ema_params_kernel(const float* __restrict__ delta,
                                  const float* __restrict__ alpha,
                                  const float* __restrict__ beta,
                                  const float* __restrict__ gamma,
                                  float* __restrict__ qArr,
                                  float* __restrict__ wArr,
                                  float* __restrict__ qLcArr,
                                  int log2Lc) {
    int i = blockIdx.x * blockDim.x + threadIdx.x;  // i = d*N + n
    if (i >= D_SZ * N_MODES) return;
    int d = i / N_MODES;
    int n = i - d * N_MODES;
    float p  = 1.0f / (1.0f + expf(-delta[i]));
    float sa = 1.0f / (1.0f + expf(-alpha[i]));
    float q  = 1.0f - p * sa;                 // in (0,1)
    const float scale = 0.25f;                // 1/sqrt(16)
    float w = p * beta[i] * gamma[i] * scale;
    float qp = q;
    for (int t = 0; t < log2Lc; ++t) qp *= qp; // q^(2^log2Lc) = q^Lc
    int o = n * D_SZ + d;
    qArr[o]   = q;
    wArr[o]   = w;
    qLcArr[o] = qp;
}

// ---------------------------------------------------------------------------
// Phase 1: per (chunk j, channel c) compute chunk-local end state
//   h_n = sum_{t in chunk} q_n^{end-t} x[t]   (h starts at 0)
// S layout: S[(j*CH + c)*16 + n]  (64B per thread, float4-stored)
// ---------------------------------------------------------------------------
__global__ __launch_bounds__(256) void ema_phase1(const float* __restrict__ x,
                                                  const float* __restrict__ qArr,
                                                  float* __restrict__ S,
                                                  int Lc) {
    int tid = threadIdx.x;
    int c = blockIdx.y * 256 + tid;   // channel = b*D + d
    int j = blockIdx.x;               // chunk
    int d = c & (D_SZ - 1);
    float q[N_MODES], h[N_MODES];
#pragma unroll
    for (int n = 0; n < N_MODES; ++n) { q[n] = qArr[n * D_SZ + d]; h[n] = 0.0f; }
    const float* xp = x + (size_t)j * Lc * ROW + c;
    for (int s = 0; s < Lc; ++s) {
        float xv = xp[(size_t)s * ROW];
#pragma unroll
        for (int n = 0; n < N_MODES; ++n) h[n] = fmaf(q[n], h[n], xv);
    }
    float4* Sp = (float4*)(S + ((size_t)j * CH + c) * N_MODES);
#pragma unroll
    for (int r = 0; r < 4; ++r)
        Sp[r] = make_float4(h[4*r], h[4*r+1], h[4*r+2], h[4*r+3]);
}

// ---------------------------------------------------------------------------
// Phase 2: scan chunk states over j for each (c,n); rewrite S in place with
// carry-IN state for each chunk:  S[j] <- H_{j-1},  H_j = qLc*H_{j-1} + S_j
// ---------------------------------------------------------------------------
__global__ __launch_bounds__(256) void ema_phase2(float* __restrict__ S,
                                                  const float* __restrict__ qLcArr,
                                                  int C) {
    int g = blockIdx.x * 256 + threadIdx.x;   // g = c*16 + n
    int c = g >> 4;
    int n = g & 15;
    int d = c & (D_SZ - 1);
    float qLc = qLcArr[n * D_SZ + d];
    float carry = 0.0f;
    for (int j = 0; j < C; ++j) {
        size_t idx = (size_t)j * (CH * N_MODES) + g;
        float s = S[idx];
        S[idx] = carry;
        carry = fmaf(qLc, carry, s);
    }
}

// ---------------------------------------------------------------------------
// Phase 3: re-run in-chunk recurrence seeded with carry-in; emit
//   out = silu( sum_n w_n h_n + x*omega )
// ---------------------------------------------------------------------------
__global__ __launch_bounds__(256) void ema_phase3(const float* __restrict__ x,
                                                  const float* __restrict__ qArr,
                                                  const float* __restrict__ wArr,
                                                  const float* __restrict__ S,
                                                  const float* __restrict__ omega,
                                                  float* __restrict__ out,
                                                  int Lc) {
    int tid = threadIdx.x;
    int c = blockIdx.y * 256 + tid;
    int j = blockIdx.x;
    int d = c & (D_SZ - 1);
    float om = omega[d];
    float q[N_MODES], w[N_MODES], h[N_MODES];
    const float4* Sp = (const float4*)(S + ((size_t)j * CH + c) * N_MODES);
#pragma unroll
    for (int r = 0; r < 4; ++r) {
        float4 v = Sp[r];
        h[4*r] = v.x; h[4*r+1] = v.y; h[4*r+2] = v.z; h[4*r+3] = v.w;
    }
#pragma unroll
    for (int n = 0; n < N_MODES; ++n) {
        q[n] = qArr[n * D_SZ + d];
        w[n] = wArr[n * D_SZ + d];
    }
    size_t base = (size_t)j * Lc * ROW + c;
    for (int s = 0; s < Lc; ++s) {
        size_t idx = base + (size_t)s * ROW;
        float xv = x[idx];
        float y0 = 0.0f, y1 = 0.0f, y2 = 0.0f, y3 = 0.0f;
#pragma unroll
        for (int n = 0; n < N_MODES; n += 4) {
            h[n]   = fmaf(q[n],   h[n],   xv); y0 = fmaf(w[n],   h[n],   y0);
            h[n+1] = fmaf(q[n+1], h[n+1], xv); y1 = fmaf(w[n+1], h[n+1], y1);
            h[n+2] = fmaf(q[n+2], h[n+2], xv); y2 = fmaf(w[n+2], h[n+2], y2);
            h[n+3] = fmaf(q[n+3], h[n+3], xv); y3 = fmaf(w[n+3], h[n+3], y3);
        }
        float z = (y0 + y1) + (y2 + y3) + xv * om;
        out[idx] = z / (1.0f + __expf(-z));   // silu
    }
}

// ---------------------------------------------------------------------------
extern "C" void kernel_launch(void* const* d_in, const int* in_sizes, int n_in,
                              void* d_out, int out_size, void* d_ws, size_t ws_size,
                              hipStream_t stream) {
    const float* x     = (const float*)d_in[0];
    const float* delta = (const float*)d_in[1];
    const float* alpha = (const float*)d_in[2];
    const float* beta  = (const float*)d_in[3];
    const float* gamma = (const float*)d_in[4];
    const float* omega = (const float*)d_in[5];
    float* out = (float*)d_out;

    const size_t paramFloats = (size_t)N_MODES * D_SZ;        // 16384
    const size_t paramBytes  = paramFloats * sizeof(float);   // 64 KB each

    // Pick chunk count C (power of 2) so ws fits: 3 param arrays + C*256KB states
    int C = 64;
    while (C > 1 &&
           3 * paramBytes + (size_t)C * CH * N_MODES * sizeof(float) > ws_size)
        C >>= 1;
    int Lc = L_SEQ / C;
    int log2Lc = 0;
    while ((1 << log2Lc) < Lc) ++log2Lc;

    float* qArr   = (float*)d_ws;
    float* wArr   = qArr   + paramFloats;
    float* qLcArr = wArr   + paramFloats;
    float* S      = qLcArr + paramFloats;

    ema_params_kernel<<<(D_SZ * N_MODES + 255) / 256, 256, 0, stream>>>(
        delta, alpha, beta, gamma, qArr, wArr, qLcArr, log2Lc);

    dim3 grid(C, CH / 256);
    ema_phase1<<<grid, 256, 0, stream>>>(x, qArr, S, Lc);
    ema_phase2<<<(CH * N_MODES) / 256, 256, 0, stream>>>(S, qLcArr, C);
    ema_phase3<<<grid, 256, 0, stream>>>(x, qArr, wArr, S, omega, out, Lc);
}

// Round 2
// 176.714 us; speedup vs baseline: 1.1331x; 1.1331x over previous
//
#include <hip/hip_runtime.h>
#include <math.h>

// Problem constants (from reference): L=4096, B=4, D=1024, N=16
#define L_SEQ 4096
#define B_SZ 4
#define D_SZ 1024
#define N_MODES 16
#define CH (B_SZ * D_SZ)   // 4096 channels (b,d)
#define ROW (B_SZ * D_SZ)  // stride between consecutive l in x: 4096 floats

// ---------------------------------------------------------------------------
// Precompute per-(d,n) parameters (transposed [n][d] for coalesced loads):
//   p = sigmoid(delta); q = 1 - p*sigmoid(alpha)
//   w = p * beta * gamma * scale   (scale = 1/sqrt(N) = 0.25)
//   qLc = q^Lc
// ---------------------------------------------------------------------------
__global__ void ema_params_kernel(const float* __restrict__ delta,
                                  const float* __restrict__ alpha,
                                  const float* __restrict__ beta,
                                  const float* __restrict__ gamma,
                                  float* __restrict__ qArr,
                                  float* __restrict__ wArr,
                                  float* __restrict__ qLcArr,
                                  int log2Lc) {
    int i = blockIdx.x * blockDim.x + threadIdx.x;  // i = d*N + n
    if (i >= D_SZ * N_MODES) return;
    int d = i / N_MODES;
    int n = i - d * N_MODES;
    float p  = 1.0f / (1.0f + expf(-delta[i]));
    float sa = 1.0f / (1.0f + expf(-alpha[i]));
    float q  = 1.0f - p * sa;                 // in (0,1)
    const float scale = 0.25f;                // 1/sqrt(16)
    float w = p * beta[i] * gamma[i] * scale;
    float qp = q;
    for (int t = 0; t < log2Lc; ++t) qp *= qp; // q^(2^log2Lc) = q^Lc
    int o = n * D_SZ + d;
    qArr[o]   = q;
    wArr[o]   = w;
    qLcArr[o] = qp;
}

// ---------------------------------------------------------------------------
// Phase 1: per (chunk j, channel c) chunk-local end state (h starts at 0).
// 8-wide load batching for memory-latency ILP.
// S layout: S[(j*CH + c)*16 + n]
// ---------------------------------------------------------------------------
__global__ __launch_bounds__(256) void ema_phase1(const float* __restrict__ x,
                                                  const float* __restrict__ qArr,
                                                  float* __restrict__ S,
                                                  int Lc) {
    int tid = threadIdx.x;
    int c = blockIdx.y * 256 + tid;   // channel = b*D + d
    int j = blockIdx.x;               // chunk
    int d = c & (D_SZ - 1);
    float q[N_MODES], h[N_MODES];
#pragma unroll
    for (int n = 0; n < N_MODES; ++n) { q[n] = qArr[n * D_SZ + d]; h[n] = 0.0f; }
    const float* xp = x + (size_t)j * Lc * ROW + c;
    int s = 0;
    for (; s + 8 <= Lc; s += 8) {
        float xv[8];
#pragma unroll
        for (int u = 0; u < 8; ++u) xv[u] = xp[(size_t)(s + u) * ROW];
#pragma unroll
        for (int u = 0; u < 8; ++u) {
#pragma unroll
            for (int n = 0; n < N_MODES; ++n) h[n] = fmaf(q[n], h[n], xv[u]);
        }
    }
    for (; s < Lc; ++s) {
        float xv = xp[(size_t)s * ROW];
#pragma unroll
        for (int n = 0; n < N_MODES; ++n) h[n] = fmaf(q[n], h[n], xv);
    }
    float4* Sp = (float4*)(S + ((size_t)j * CH + c) * N_MODES);
#pragma unroll
    for (int r = 0; r < 4; ++r)
        Sp[r] = make_float4(h[4*r], h[4*r+1], h[4*r+2], h[4*r+3]);
}

// ---------------------------------------------------------------------------
// Phase 2: scan chunk states over j per (c,n); rewrite S in place with the
// carry-IN state for each chunk:  S[j] <- H_{j-1},  H_j = qLc*H_{j-1} + S_j
// 4-wide load batching (loads are address-independent).
// ---------------------------------------------------------------------------
__global__ __launch_bounds__(256) void ema_phase2(float* __restrict__ S,
                                                  const float* __restrict__ qLcArr,
                                                  int C) {
    int g = blockIdx.x * 256 + threadIdx.x;   // g = c*16 + n
    int c = g >> 4;
    int n = g & 15;
    int d = c & (D_SZ - 1);
    float qLc = qLcArr[n * D_SZ + d];
    float carry = 0.0f;
    const size_t stride = (size_t)CH * N_MODES;
    int j = 0;
    for (; j + 4 <= C; j += 4) {
        size_t i0 = (size_t)j * stride + g;
        float s0 = S[i0];
        float s1 = S[i0 + stride];
        float s2 = S[i0 + 2 * stride];
        float s3 = S[i0 + 3 * stride];
        S[i0]              = carry; carry = fmaf(qLc, carry, s0);
        S[i0 + stride]     = carry; carry = fmaf(qLc, carry, s1);
        S[i0 + 2 * stride] = carry; carry = fmaf(qLc, carry, s2);
        S[i0 + 3 * stride] = carry; carry = fmaf(qLc, carry, s3);
    }
    for (; j < C; ++j) {
        size_t idx = (size_t)j * stride + g;
        float s = S[idx];
        S[idx] = carry;
        carry = fmaf(qLc, carry, s);
    }
}

// ---------------------------------------------------------------------------
// Phase 3: re-run in-chunk recurrence seeded with carry-in; emit
//   out = silu( sum_n w_n h_n + x*omega ).  8-wide load batching.
// ---------------------------------------------------------------------------
__global__ __launch_bounds__(256) void ema_phase3(const float* __restrict__ x,
                                                  const float* __restrict__ qArr,
                                                  const float* __restrict__ wArr,
                                                  const float* __restrict__ S,
                                                  const float* __restrict__ omega,
                                                  float* __restrict__ out,
                                                  int Lc) {
    int tid = threadIdx.x;
    int c = blockIdx.y * 256 + tid;
    int j = blockIdx.x;
    int d = c & (D_SZ - 1);
    float om = omega[d];
    float q[N_MODES], w[N_MODES], h[N_MODES];
    const float4* Sp = (const float4*)(S + ((size_t)j * CH + c) * N_MODES);
#pragma unroll
    for (int r = 0; r < 4; ++r) {
        float4 v = Sp[r];
        h[4*r] = v.x; h[4*r+1] = v.y; h[4*r+2] = v.z; h[4*r+3] = v.w;
    }
#pragma unroll
    for (int n = 0; n < N_MODES; ++n) {
        q[n] = qArr[n * D_SZ + d];
        w[n] = wArr[n * D_SZ + d];
    }
    size_t base = (size_t)j * Lc * ROW + c;
    int s = 0;
    for (; s + 8 <= Lc; s += 8) {
        float xv[8];
#pragma unroll
        for (int u = 0; u < 8; ++u) xv[u] = x[base + (size_t)(s + u) * ROW];
#pragma unroll
        for (int u = 0; u < 8; ++u) {
            float y0 = 0.0f, y1 = 0.0f, y2 = 0.0f, y3 = 0.0f;
            float xu = xv[u];
#pragma unroll
            for (int n = 0; n < N_MODES; n += 4) {
                h[n]   = fmaf(q[n],   h[n],   xu); y0 = fmaf(w[n],   h[n],   y0);
                h[n+1] = fmaf(q[n+1], h[n+1], xu); y1 = fmaf(w[n+1], h[n+1], y1);
                h[n+2] = fmaf(q[n+2], h[n+2], xu); y2 = fmaf(w[n+2], h[n+2], y2);
                h[n+3] = fmaf(q[n+3], h[n+3], xu); y3 = fmaf(w[n+3], h[n+3], y3);
            }
            float z = (y0 + y1) + (y2 + y3) + xu * om;
            float r = z / (1.0f + __expf(-z));    // silu
            __builtin_nontemporal_store(r, &out[base + (size_t)(s + u) * ROW]);
        }
    }
    for (; s < Lc; ++s) {
        float xu = x[base + (size_t)s * ROW];
        float y0 = 0.0f, y1 = 0.0f, y2 = 0.0f, y3 = 0.0f;
#pragma unroll
        for (int n = 0; n < N_MODES; n += 4) {
            h[n]   = fmaf(q[n],   h[n],   xu); y0 = fmaf(w[n],   h[n],   y0);
            h[n+1] = fmaf(q[n+1], h[n+1], xu); y1 = fmaf(w[n+1], h[n+1], y1);
            h[n+2] = fmaf(q[n+2], h[n+2], xu); y2 = fmaf(w[n+2], h[n+2], y2);
            h[n+3] = fmaf(q[n+3], h[n+3], xu); y3 = fmaf(w[n+3], h[n+3], y3);
        }
        float z = (y0 + y1) + (y2 + y3) + xu * om;
        float r = z / (1.0f + __expf(-z));
        __builtin_nontemporal_store(r, &out[base + (size_t)s * ROW]);
    }
}

// ---------------------------------------------------------------------------
extern "C" void kernel_launch(void* const* d_in, const int* in_sizes, int n_in,
                              void* d_out, int out_size, void* d_ws, size_t ws_size,
                              hipStream_t stream) {
    const float* x     = (const float*)d_in[0];
    const float* delta = (const float*)d_in[1];
    const float* alpha = (const float*)d_in[2];
    const float* beta  = (const float*)d_in[3];
    const float* gamma = (const float*)d_in[4];
    const float* omega = (const float*)d_in[5];
    float* out = (float*)d_out;

    const size_t paramFloats = (size_t)N_MODES * D_SZ;        // 16384
    const size_t paramBytes  = paramFloats * sizeof(float);   // 64 KB each

    // Pick chunk count C (power of 2) so ws fits: 3 param arrays + C*(CH*16*4B)
    // C=128 -> Lc=32, 2048 blocks (8 blocks/CU, full wave occupancy)
    int C = 128;
    while (C > 1 &&
           3 * paramBytes + (size_t)C * CH * N_MODES * sizeof(float) > ws_size)
        C >>= 1;
    int Lc = L_SEQ / C;
    int log2Lc = 0;
    while ((1 << log2Lc) < Lc) ++log2Lc;

    float* qArr   = (float*)d_ws;
    float* wArr   = qArr   + paramFloats;
    float* qLcArr = wArr   + paramFloats;
    float* S      = qLcArr + paramFloats;

    ema_params_kernel<<<(D_SZ * N_MODES + 255) / 256, 256, 0, stream>>>(
        delta, alpha, beta, gamma, qArr, wArr, qLcArr, log2Lc);

    dim3 grid(C, CH / 256);
    ema_phase1<<<grid, 256, 0, stream>>>(x, qArr, S, Lc);
    ema_phase2<<<(CH * N_MODES) / 256, 256, 0, stream>>>(S, qLcArr, C);
    ema_phase3<<<grid, 256, 0, stream>>>(x, qArr, wArr, S, omega, out, Lc);
}

// Round 4
// 164.489 us; speedup vs baseline: 1.2173x; 1.0743x over previous
//
#include <hip/hip_runtime.h>
#include <hip/hip_cooperative_groups.h>
#include <math.h>

namespace cg = cooperative_groups;

// Problem constants: L=4096, B=4, D=1024, N=16
#define D_SZ 1024
#define N_MODES 16
#define CH 4096          // B*D channels
#define ROW 4096         // x stride between consecutive l
#define C_CHUNKS 64
#define LC 64            // L / C_CHUNKS

// ---------------------------------------------------------------------------
// Param helpers: q = 1 - sigmoid(delta)*sigmoid(alpha), w = sigmoid(delta)*beta*gamma*0.25
// ---------------------------------------------------------------------------
__device__ __forceinline__ void load16(const float* __restrict__ p, int d, float v[16]) {
    const float4* p4 = (const float4*)(p + (size_t)d * 16);
#pragma unroll
    for (int r = 0; r < 4; ++r) {
        float4 t = p4[r];
        v[4*r+0] = t.x; v[4*r+1] = t.y; v[4*r+2] = t.z; v[4*r+3] = t.w;
    }
}

__device__ __forceinline__ void compute_qw(const float* __restrict__ delta,
                                           const float* __restrict__ alpha,
                                           const float* __restrict__ beta,
                                           const float* __restrict__ gamma,
                                           int d, float q[16], float w[16]) {
    float dl[16], al[16], bt[16], gm[16];
    load16(delta, d, dl); load16(alpha, d, al);
    load16(beta, d, bt);  load16(gamma, d, gm);
#pragma unroll
    for (int n = 0; n < 16; ++n) {
        float p  = 1.0f / (1.0f + __expf(-dl[n]));
        float sa = 1.0f / (1.0f + __expf(-al[n]));
        q[n] = 1.0f - p * sa;
        w[n] = p * bt[n] * gm[n] * 0.25f;   // scale = 1/sqrt(16)
    }
}

// ---------------------------------------------------------------------------
// Phase 1: chunk-local end state (h from 0), 8-wide load batching.
// S layout: S[(j*CH + c)*16 + n]
// ---------------------------------------------------------------------------
__device__ __forceinline__ void phase1_body(const float* __restrict__ x, float* __restrict__ S,
    const float* __restrict__ delta, const float* __restrict__ alpha,
    const float* __restrict__ beta, const float* __restrict__ gamma, int j, int c) {
    int d = c & (D_SZ - 1);
    float q[16], w[16];
    compute_qw(delta, alpha, beta, gamma, d, q, w);   // w is dead here -> DCE
    float h[16];
#pragma unroll
    for (int n = 0; n < 16; ++n) h[n] = 0.0f;
    const float* xp = x + (size_t)j * (LC * ROW) + c;
#pragma unroll 2
    for (int s0 = 0; s0 < LC; s0 += 8) {
        float xv[8];
#pragma unroll
        for (int u = 0; u < 8; ++u) xv[u] = xp[(size_t)(s0 + u) * ROW];
#pragma unroll
        for (int u = 0; u < 8; ++u)
#pragma unroll
            for (int n = 0; n < 16; ++n) h[n] = fmaf(q[n], h[n], xv[u]);
    }
    float4* Sp = (float4*)(S + ((size_t)j * CH + c) * 16);
#pragma unroll
    for (int r = 0; r < 4; ++r)
        Sp[r] = make_float4(h[4*r], h[4*r+1], h[4*r+2], h[4*r+3]);
}

// ---------------------------------------------------------------------------
// Phase 2: wave-parallel Kogge-Stone scan over chunks. One wave per channel,
// lane = chunk j. Rewrites S with the carry-IN state per chunk.
//   H_j = S_j + qLc * H_{j-1};  carry-in(j) = H_{j-1}
// ---------------------------------------------------------------------------
__device__ __forceinline__ void phase2_body(float* __restrict__ S,
    const float* __restrict__ delta, const float* __restrict__ alpha, int c2, int lane) {
    int d = c2 & (D_SZ - 1);
    float dl[16], al[16];
    load16(delta, d, dl); load16(alpha, d, al);
    float pw[16];
#pragma unroll
    for (int n = 0; n < 16; ++n) {
        float p  = 1.0f / (1.0f + __expf(-dl[n]));
        float sa = 1.0f / (1.0f + __expf(-al[n]));
        float qn = 1.0f - p * sa;
#pragma unroll
        for (int t = 0; t < 6; ++t) qn *= qn;   // q^64 = q^LC
        pw[n] = qn;
    }
    float hh[16];
    float4* Sp = (float4*)(S + ((size_t)lane * CH + c2) * 16);
#pragma unroll
    for (int r = 0; r < 4; ++r) {
        float4 t = Sp[r];
        hh[4*r] = t.x; hh[4*r+1] = t.y; hh[4*r+2] = t.z; hh[4*r+3] = t.w;
    }
#pragma unroll
    for (int k = 1; k <= 32; k <<= 1) {
        float prev[16];
#pragma unroll
        for (int n = 0; n < 16; ++n) prev[n] = __shfl_up(hh[n], (unsigned)k, 64);
#pragma unroll
        for (int n = 0; n < 16; ++n) hh[n] = (lane >= k) ? fmaf(pw[n], prev[n], hh[n]) : hh[n];
#pragma unroll
        for (int n = 0; n < 16; ++n) pw[n] *= pw[n];
    }
    float cin[16];
#pragma unroll
    for (int n = 0; n < 16; ++n) {
        float t = __shfl_up(hh[n], 1u, 64);
        cin[n] = (lane == 0) ? 0.0f : t;
    }
#pragma unroll
    for (int r = 0; r < 4; ++r)
        Sp[r] = make_float4(cin[4*r], cin[4*r+1], cin[4*r+2], cin[4*r+3]);
}

// ---------------------------------------------------------------------------
// Phase 3: recurrence seeded with carry-in; out = silu(sum_n w_n h_n + x*omega)
// ---------------------------------------------------------------------------
__device__ __forceinline__ void phase3_body(const float* __restrict__ x,
    const float* __restrict__ S, float* __restrict__ out,
    const float* __restrict__ delta, const float* __restrict__ alpha,
    const float* __restrict__ beta, const float* __restrict__ gamma,
    const float* __restrict__ omega, int j, int c) {
    int d = c & (D_SZ - 1);
    float q[16], w[16];
    compute_qw(delta, alpha, beta, gamma, d, q, w);
    float om = omega[d];
    float h[16];
    const float4* Sp = (const float4*)(S + ((size_t)j * CH + c) * 16);
#pragma unroll
    for (int r = 0; r < 4; ++r) {
        float4 t = Sp[r];
        h[4*r] = t.x; h[4*r+1] = t.y; h[4*r+2] = t.z; h[4*r+3] = t.w;
    }
    size_t base = (size_t)j * (LC * ROW) + c;
#pragma unroll 2
    for (int s0 = 0; s0 < LC; s0 += 8) {
        float xv[8];
#pragma unroll
        for (int u = 0; u < 8; ++u) xv[u] = x[base + (size_t)(s0 + u) * ROW];
#pragma unroll
        for (int u = 0; u < 8; ++u) {
            float xu = xv[u];
            float y0 = 0.0f, y1 = 0.0f, y2 = 0.0f, y3 = 0.0f;
#pragma unroll
            for (int n = 0; n < 16; n += 4) {
                h[n]   = fmaf(q[n],   h[n],   xu); y0 = fmaf(w[n],   h[n],   y0);
                h[n+1] = fmaf(q[n+1], h[n+1], xu); y1 = fmaf(w[n+1], h[n+1], y1);
                h[n+2] = fmaf(q[n+2], h[n+2], xu); y2 = fmaf(w[n+2], h[n+2], y2);
                h[n+3] = fmaf(q[n+3], h[n+3], xu); y3 = fmaf(w[n+3], h[n+3], y3);
            }
            float z = (y0 + y1) + (y2 + y3) + xu * om;
            float r = z / (1.0f + __expf(-z));   // silu
            __builtin_nontemporal_store(r, &out[base + (size_t)(s0 + u) * ROW]);
        }
    }
}

// ---------------------------------------------------------------------------
// Fused cooperative kernel: 1024 blocks x 256 thr = 4 blocks/CU co-resident.
// ---------------------------------------------------------------------------
__global__ __launch_bounds__(256, 4) void ema_fused(
    const float* __restrict__ x, const float* __restrict__ delta,
    const float* __restrict__ alpha, const float* __restrict__ beta,
    const float* __restrict__ gamma, const float* __restrict__ omega,
    float* __restrict__ S, float* __restrict__ out) {
    int tid = threadIdx.x;
    int j = blockIdx.x;                    // chunk
    int c = blockIdx.y * 256 + tid;        // channel
    phase1_body(x, S, delta, alpha, beta, gamma, j, c);
    cg::this_grid().sync();
    int gb = blockIdx.y * gridDim.x + blockIdx.x;       // 0..1023
    phase2_body(S, delta, alpha, gb * 4 + (tid >> 6), tid & 63);
    cg::this_grid().sync();
    phase3_body(x, S, out, delta, alpha, beta, gamma, omega, j, c);
}

// Fallback (non-cooperative) pipeline — same device code, 3 dispatches.
__global__ __launch_bounds__(256) void k_phase1(const float* __restrict__ x, float* __restrict__ S,
    const float* __restrict__ delta, const float* __restrict__ alpha,
    const float* __restrict__ beta, const float* __restrict__ gamma) {
    phase1_body(x, S, delta, alpha, beta, gamma, blockIdx.x, blockIdx.y * 256 + threadIdx.x);
}
__global__ __launch_bounds__(256) void k_phase2(float* __restrict__ S,
    const float* __restrict__ delta, const float* __restrict__ alpha) {
    phase2_body(S, delta, alpha, blockIdx.x * 4 + (threadIdx.x >> 6), threadIdx.x & 63);
}
__global__ __launch_bounds__(256) void k_phase3(const float* __restrict__ x,
    const float* __restrict__ S, float* __restrict__ out,
    const float* __restrict__ delta, const float* __restrict__ alpha,
    const float* __restrict__ beta, const float* __restrict__ gamma,
    const float* __restrict__ omega) {
    phase3_body(x, S, out, delta, alpha, beta, gamma, omega,
                blockIdx.x, blockIdx.y * 256 + threadIdx.x);
}

// ---------------------------------------------------------------------------
extern "C" void kernel_launch(void* const* d_in, const int* in_sizes, int n_in,
                              void* d_out, int out_size, void* d_ws, size_t ws_size,
                              hipStream_t stream) {
    const float* x     = (const float*)d_in[0];
    const float* delta = (const float*)d_in[1];
    const float* alpha = (const float*)d_in[2];
    const float* beta  = (const float*)d_in[3];
    const float* gamma = (const float*)d_in[4];
    const float* omega = (const float*)d_in[5];
    float* out = (float*)d_out;
    float* S   = (float*)d_ws;             // 64*4096*16*4B = 16.8 MB

    dim3 grid(C_CHUNKS, CH / 256);         // (64,16) = 1024 blocks

    // Deterministic every call (no static guards): coop path only if 4 blocks/CU fit.
    int maxBlocks = 0;
    hipError_t e = hipOccupancyMaxActiveBlocksPerMultiprocessor(
        &maxBlocks, (const void*)ema_fused, 256, 0);
    if (e == hipSuccess && maxBlocks >= 4) {
        void* args[] = {(void*)&x, (void*)&delta, (void*)&alpha, (void*)&beta,
                        (void*)&gamma, (void*)&omega, (void*)&S, (void*)&out};
        hipLaunchCooperativeKernel((const void*)ema_fused, grid, dim3(256, 1, 1),
                                   args, 0, stream);
    } else {
        k_phase1<<<grid, 256, 0, stream>>>(x, S, delta, alpha, beta, gamma);
        k_phase2<<<CH / 4, 256, 0, stream>>>(S, delta, alpha);
        k_phase3<<<grid, 256, 0, stream>>>(x, S, out, delta, alpha, beta, gamma, omega);
    }
}